// Round 11
// baseline (603.213 us; speedup 1.0000x reference)
//
#include <hip/hip_runtime.h>
#include <hip/hip_bf16.h>
#include <math.h>

#define DM   512
#define TT   1024
#define NB   4
#define NHD  8
#define LAYERS 6
#define DFFD 1024
#define MROWS (NB*TT)          // 4096
#define PERBUF (NB*NHD*TT*64)  // 2097152 elems per Q/K/V buffer

typedef __bf16 bf16x8 __attribute__((ext_vector_type(8)));
typedef __bf16 bf16x4 __attribute__((ext_vector_type(4)));
typedef float f32x4 __attribute__((ext_vector_type(4)));

// async global->LDS, 16B per lane; LDS base must be wave-uniform (m104/m108)
__device__ __forceinline__ void gl_lds16(const __bf16* g, __bf16* l) {
    __builtin_amdgcn_global_load_lds((const __attribute__((address_space(1))) void*)g,
                                     (__attribute__((address_space(3))) void*)l, 16, 0, 0);
}

// split-KV chunk tables (NCHUNK=24): qt 0-7 one chunk, qt 8-15 two chunks.
// Ordered heavy-first (u=0 dispatched first carries longest chains).
__constant__ signed char C_QT[24]  = {15,15,14, 7,14,13,13,12, 6,12,11,11,10, 5,10, 9, 9, 8, 4, 8, 3, 2, 1, 0};
__constant__ signed char C_ST0[24] = { 0, 8, 0, 0, 8, 0, 7, 0, 0, 7, 0, 6, 0, 0, 6, 0, 5, 0, 0, 5, 0, 0, 0, 0};
__constant__ signed char C_ST1[24] = { 8,16, 8, 8,15, 7,14, 7, 7,13, 6,12, 6, 6,11, 5,10, 5, 5, 9, 4, 3, 2, 1};
// combine: qt -> chunk ids (second valid only for qt>=8)
__constant__ unsigned char C_UA[16] = {23,22,21,20,18,13,8,3,17,15,12,10,7,5,2,0};
__constant__ unsigned char C_UB[16] = { 0, 0, 0, 0, 0, 0,0,0,19,16,14,11,9,6,4,1};
#define NCHUNK 24

// ---------------- embedding + positional encoding (bf16 residual stream) ----------------
__global__ __launch_bounds__(256) void embed_pos_kernel(const int* __restrict__ x,
    const float* __restrict__ emb, __bf16* __restrict__ hb)
{
    int row = blockIdx.x;            // n*T + t
    int t = row & (TT - 1);
    int tok = x[row];
    const float* e = emb + (size_t)tok * DM;
    __bf16* outb = hb + (size_t)row * DM;
    for (int i = threadIdx.x; i < DM; i += 256) {
        float val = e[i] * 22.62741699796952f;   // sqrt(512)
        int pair = i >> 1;
        // 10000^(-pair/256) = exp2(-pair * log2(10000)/256)
        float rate = exp2f((float)pair * -0.051905126482615035f);
        float ang = (float)t * rate;
        float pe = (i & 1) ? __cosf(ang) : __sinf(ang);
        outb[i] = (__bf16)(val + pe);
    }
}

// ---------------- all-weight convert + transpose (one dispatch) ----------------
// W[K,N] fp32 -> Wt[N,K] bf16. For Wqkv, output columns are PERMUTED:
// original col c -> row (c%3)*512 + c/3, grouping Q|K|V with inner [h][d].
__global__ __launch_bounds__(256) void convert_all_kernel(
    const float* __restrict__ Wqkv, const float* __restrict__ Wff, const float* __restrict__ Wo,
    const float* __restrict__ bqkv,
    __bf16* __restrict__ WtQ, __bf16* __restrict__ WtF, __bf16* __restrict__ WtO,
    float* __restrict__ bqkv_p)
{
    __shared__ float tile[32][33];
    int l = blockIdx.z;
    int t = blockIdx.x;
    const float* W; __bf16* Wt; int K, N, bx, by; bool perm = false;
    if (t < 768)       { W = Wqkv; Wt = WtQ; K = 512;  N = 1536; bx = t & 15;  by = t >> 4; perm = true; }
    else if (t < 1280) { int u = t - 768;  W = Wff; Wt = WtF; K = 512;  N = 1024; bx = u & 15; by = u >> 4; }
    else               { int u = t - 1280; W = Wo;  Wt = WtO; K = 1024; N = 512;  bx = u & 31; by = u >> 5; }
    int k0 = bx * 32, n0 = by * 32;
    const float* Wl = W + (size_t)l * K * N;
    __bf16* Wtl = Wt + (size_t)l * K * N;
    int tx = threadIdx.x & 31, ty = threadIdx.x >> 5;   // ty 0..7
    #pragma unroll
    for (int i = ty; i < 32; i += 8)
        tile[i][tx] = Wl[(size_t)(k0 + i) * N + n0 + tx];
    if (perm && bx == 0 && ty == 0) {                   // permute bias once per col-chunk
        int c = n0 + tx;
        bqkv_p[l * 1536 + (c % 3) * 512 + c / 3] = bqkv[(size_t)l * 1536 + c];
    }
    __syncthreads();
    #pragma unroll
    for (int i = ty; i < 32; i += 8) {
        int c = n0 + i;
        int row = perm ? ((c % 3) * 512 + c / 3) : c;
        Wtl[(size_t)row * K + k0 + tx] = (__bf16)tile[tx][i];
    }
}

// ---------------- bf16 MFMA GEMM, templated tile, 2-phase pipelined 32-K panels ----------------
// R11: QKV/FF1 shrink to 64x64 tiles -> 1536/1024 blocks (6/4 per CU, was 3/2):
// more waves/SIMD to hide the barrier drains (R5's proven lever, one more notch).
// LDS reads swizzled conflict-free (R7). Fragment loads via LDS (R4 lesson).
// MODE 0: bf16 C out (+bias, no relu). MODE 1: relu -> bf16. MODE 2: QKV scatter, PERMUTED cols:
// c in [0,512)=Q, [512,1024)=K (both [n,h,t,d]), [1024,1536)=V^T [n,h,d,t].
template<int BM, int BN, int MODE>
__global__ __launch_bounds__(256) void gemm2p(const __bf16* __restrict__ A,
    const __bf16* __restrict__ Bt, const float* __restrict__ bias,
    void* __restrict__ Cv, int M, int Nc, int K)
{
    constexpr int WM = BM / 2, WN = BN / 2;
    constexpr int MT = WM / 16, NT = WN / 16;
    constexpr int ACH = BM / 64;   // 16-row A chunks staged per wave
    constexpr int BCH = BN / 64;   // 16-row B chunks staged per wave
    __shared__ __align__(16) __bf16 As[2][BM * 32];
    __shared__ __align__(16) __bf16 Bs[2][BN * 32];
    int tid = threadIdx.x;
    int lane = tid & 63;
    int wave = tid >> 6;
    int ln = lane & 15, q = lane >> 4;
    int wrow = (wave >> 1) * WM, wcol = (wave & 1) * WN;
    int n0 = blockIdx.x * BN, m0 = blockIdx.y * BM;

    f32x4 acc[MT][NT] = {};

    const __bf16* Ab = A + (size_t)m0 * K;
    const __bf16* Bb = Bt + (size_t)n0 * K;
    int srow = lane >> 2;                                  // 0..15
    int scol = ((lane & 3) ^ ((lane >> 3) & 3)) * 8;       // pre-swizzled source slot
    int kx   = (q ^ ((ln >> 1) & 3)) * 8;                  // read-side swizzled slot

    const __bf16* Aga[ACH];
    const __bf16* Bga[BCH];
    #pragma unroll
    for (int i = 0; i < ACH; i++)
        Aga[i] = Ab + (size_t)(wave * (16 * ACH) + 16 * i + srow) * K + scol;
    #pragma unroll
    for (int i = 0; i < BCH; i++)
        Bga[i] = Bb + (size_t)(wave * (16 * BCH) + 16 * i + srow) * K + scol;

    auto STAGE = [&](int kp, int buf) {
        #pragma unroll
        for (int i = 0; i < ACH; i++)
            gl_lds16(Aga[i] + kp, As[buf] + (wave * (16 * ACH) + 16 * i) * 32);
        #pragma unroll
        for (int i = 0; i < BCH; i++)
            gl_lds16(Bga[i] + kp, Bs[buf] + (wave * (16 * BCH) + 16 * i) * 32);
    };
    auto COMPUTE = [&](int buf) {
        bf16x8 af[MT], bfr[NT];
        #pragma unroll
        for (int mt = 0; mt < MT; mt++)
            af[mt] = *(const bf16x8*)&As[buf][(wrow + mt * 16 + ln) * 32 + kx];
        #pragma unroll
        for (int nt = 0; nt < NT; nt++)
            bfr[nt] = *(const bf16x8*)&Bs[buf][(wcol + nt * 16 + ln) * 32 + kx];
        #pragma unroll
        for (int mt = 0; mt < MT; mt++)
            #pragma unroll
            for (int nt = 0; nt < NT; nt++)
                acc[mt][nt] = __builtin_amdgcn_mfma_f32_16x16x32_bf16(af[mt], bfr[nt], acc[mt][nt], 0, 0, 0);
    };

    STAGE(0, 0);
    __syncthreads();
    int kp = 0;
    for (; kp + 64 < K; kp += 64) {
        STAGE(kp + 32, 1);
        COMPUTE(0);
        __syncthreads();      // drain: panel kp+32 landed; buf0 readers done
        STAGE(kp + 64, 0);
        COMPUTE(1);
        __syncthreads();      // drain: panel kp+64 landed; buf1 readers done
    }
    STAGE(kp + 32, 1);
    COMPUTE(0);
    __syncthreads();
    COMPUTE(1);

    #pragma unroll
    for (int mt = 0; mt < MT; mt++) {
        int mbase = m0 + wrow + mt * 16 + q * 4;
        if constexpr (MODE == 0) {
            __bf16* Cb = (__bf16*)Cv;
            #pragma unroll
            for (int r = 0; r < 4; r++) {
                int m = mbase + r;
                #pragma unroll
                for (int nt = 0; nt < NT; nt++) {
                    int c = n0 + wcol + nt * 16 + ln;
                    Cb[(size_t)m * Nc + c] = (__bf16)(acc[mt][nt][r] + bias[c]);
                }
            }
        } else if constexpr (MODE == 1) {
            __bf16* Cb = (__bf16*)Cv;
            #pragma unroll
            for (int r = 0; r < 4; r++) {
                int m = mbase + r;
                #pragma unroll
                for (int nt = 0; nt < NT; nt++) {
                    int c = n0 + wcol + nt * 16 + ln;
                    float val = acc[mt][nt][r] + bias[c];
                    Cb[(size_t)m * Nc + c] = (__bf16)fmaxf(val, 0.f);
                }
            }
        } else {
            __bf16* Cb = (__bf16*)Cv;
            int n = mbase >> 10, t = mbase & (TT - 1);
            #pragma unroll
            for (int nt = 0; nt < NT; nt++) {
                int c = n0 + wcol + nt * 16 + ln;
                int buf = c >> 9;            // uniform within the 16-col group
                int hd = c & 511;
                int hh = hd >> 6, d = hd & 63;
                float bv = bias[c];
                if (buf == 2) {              // V^T [n,h,d,t]: 4 consecutive t -> one 8B store
                    size_t idx = 2 * (size_t)PERBUF + (((size_t)(n * NHD + hh) * 64 + d) << 10) + t;
                    bf16x4 v4;
                    #pragma unroll
                    for (int r = 0; r < 4; r++) v4[r] = (__bf16)(acc[mt][nt][r] + bv);
                    *(bf16x4*)&Cb[idx] = v4;
                } else {                     // Q,K [n,h,t,d]
                    size_t base = (size_t)buf * PERBUF + (((size_t)(n * NHD + hh) * TT + t) << 6) + d;
                    #pragma unroll
                    for (int r = 0; r < 4; r++)
                        Cb[base + (size_t)(r << 6)] = (__bf16)(acc[mt][nt][r] + bv);
                }
            }
        }
    }
}

// ---------------- split-KV MFMA flash attention (NCHUNK=24, table-driven) ----------------
// Q fragments in registers. K single-buffered + V double-buffered in LDS via
// async global_load_lds with XOR-swizzled source (linear dest, swizzled read).
// QK^T computed SWAPPED (S^T = K Q^T): lane holds 4 consecutive s per q-row ->
// P store is 4x bf16x4, den reduction 2 shuffles. 768 blocks (3/CU), chains <= 8.
// po partials stored BF16 (R8): MFMA accum stays f32.
#define PPAD 72
__global__ __launch_bounds__(256) void attn_partial_kernel(const __bf16* __restrict__ qb,
    const __bf16* __restrict__ kb, const __bf16* __restrict__ vtb,
    __bf16* __restrict__ po, float* __restrict__ pden)
{
    __shared__ __align__(16) __bf16 Ksh[64 * 64];      // K tile [s][d], swizzled
    __shared__ __align__(16) __bf16 Vsh[2][64 * 64];   // V^T tile [d][s], swizzled
    __shared__ __align__(16) __bf16 Ps[64 * PPAD];     // P tile [q][s], padded

    int u = blockIdx.x;                  // heavy chunks at low u (dispatch first)
    int nh = blockIdx.y;
    int qt  = C_QT[u];
    int st0 = C_ST0[u];
    int st1 = C_ST1[u];

    int tid = threadIdx.x;
    int lane = tid & 63, w = tid >> 6;
    int ln = lane & 15, q = lane >> 4;

    const __bf16* Kg = kb + (size_t)nh * TT * 64;
    const __bf16* Vg = vtb + (size_t)nh * 64 * TT;   // [d][t]

    // Q fragments in registers: wave w owns q-rows w*16..+16 of this q-tile
    const __bf16* Qrow = qb + ((size_t)nh * TT + (size_t)qt * 64 + w * 16 + ln) * 64;
    bf16x8 aq0 = *(const bf16x8*)(Qrow + q * 8);
    bf16x8 aq1 = *(const bf16x8*)(Qrow + 32 + q * 8);

    // staging geometry: wave w issue i covers LDS bytes [(w*2+i)*1024, +1024)
    // lane l -> row (w*2+i)*8 + (l>>3), col16 l&7; source col pre-swizzled.
    int srow = lane >> 3;                        // 0..7  == (row & 7)
    int swz  = ((lane & 7) ^ srow) << 3;         // swizzled source col (elems)
    int r0 = (w * 2 + 0) * 8 + srow;
    int r1 = (w * 2 + 1) * 8 + srow;
    const __bf16* Kg0 = Kg + (size_t)r0 * 64 + swz;
    const __bf16* Kg1 = Kg + (size_t)r1 * 64 + swz;
    const __bf16* Vg0 = Vg + (size_t)r0 * TT + swz;
    const __bf16* Vg1 = Vg + (size_t)r1 * TT + swz;
    __bf16* Kd0 = Ksh + (w * 2 + 0) * 512;
    __bf16* Kd1 = Ksh + (w * 2 + 1) * 512;

    f32x4 o_acc[4] = {};
    float den_lane = 0.f;          // partial softmax denom for q-row w*16+ln
    int qrow_l = w * 16 + ln;

    int cur = 0;
    gl_lds16(Kg0 + st0 * 4096, Kd0);
    gl_lds16(Kg1 + st0 * 4096, Kd1);
    gl_lds16(Vg0 + st0 * 64, Vsh[0] + (w * 2 + 0) * 512);
    gl_lds16(Vg1 + st0 * 64, Vsh[0] + (w * 2 + 1) * 512);

    int kswz = ln & 7;   // row&7 for all swizzled reads below (rows stride 16)
    for (int st = st0; st < st1; st++) {
        __syncthreads();   // staged K/V landed (vmcnt drain); prior P/V readers done

        // S^T = K Q^T: wave w computes S^T[all 64 s][its 16 q-cols]
        f32x4 st_acc[4] = {};
        #pragma unroll
        for (int mt = 0; mt < 4; mt++) {
            int r = mt * 16 + ln;
            bf16x8 k0v = *(const bf16x8*)&Ksh[r * 64 + ((q ^ kswz) << 3)];
            st_acc[mt] = __builtin_amdgcn_mfma_f32_16x16x32_bf16(k0v, aq0, st_acc[mt], 0, 0, 0);
            bf16x8 k1v = *(const bf16x8*)&Ksh[r * 64 + (((q + 4) ^ kswz) << 3)];
            st_acc[mt] = __builtin_amdgcn_mfma_f32_16x16x32_bf16(k1v, aq1, st_acc[mt], 0, 0, 0);
        }

        // P = exp(S/8), causal mask on diagonal tile. Lane holds 4 consecutive s
        // (mt*16 + q*4 + r) for its q-row -> one bf16x4 store per mt.
        bool diag = (st == qt);
        #pragma unroll
        for (int mt = 0; mt < 4; mt++) {
            int s0i = mt * 16 + q * 4;
            bf16x4 p4;
            #pragma unroll
            for (int r = 0; r < 4; r++) {
                float p;
                if (diag && (s0i + r) > qrow_l) p = 0.f;
                else p = exp2f(st_acc[mt][r] * 0.18033688011112042f);  // /8 * log2(e)
                den_lane += p;
                p4[r] = (__bf16)p;
            }
            *(bf16x4*)&Ps[qrow_l * PPAD + s0i] = p4;
        }
        __syncthreads();   // P visible; all waves done reading K

        if (st + 1 < st1) {   // prefetch next tile under PV (K dead, V alt buffer)
            gl_lds16(Kg0 + (st + 1) * 4096, Kd0);
            gl_lds16(Kg1 + (st + 1) * 4096, Kd1);
            gl_lds16(Vg0 + (st + 1) * 64, Vsh[cur ^ 1] + (w * 2 + 0) * 512);
            gl_lds16(Vg1 + (st + 1) * 64, Vsh[cur ^ 1] + (w * 2 + 1) * 512);
        }

        // O^T += V^T P^T : wave w owns d-rows w*16..+16, all 64 q-cols
        #pragma unroll
        for (int ks = 0; ks < 2; ks++) {
            bf16x8 af = *(const bf16x8*)&Vsh[cur][(w * 16 + ln) * 64 + (((ks * 4 + q) ^ kswz) << 3)];
            #pragma unroll
            for (int nt = 0; nt < 4; nt++) {
                bf16x8 bfr = *(const bf16x8*)&Ps[(nt * 16 + ln) * PPAD + ks * 32 + q * 8];
                o_acc[nt] = __builtin_amdgcn_mfma_f32_16x16x32_bf16(af, bfr, o_acc[nt], 0, 0, 0);
            }
        }
        cur ^= 1;
    }

    // den: lanes {ln, ln+16, ln+32, ln+48} hold s-partitions of q-row w*16+ln
    den_lane += __shfl_xor(den_lane, 16, 64);
    den_lane += __shfl_xor(den_lane, 32, 64);
    size_t slot = (size_t)nh * NCHUNK + u;
    if (lane < 16)
        pden[slot * 64 + qrow_l] = den_lane;

    #pragma unroll
    for (int nt = 0; nt < 4; nt++) {
        bf16x4 ov;
        #pragma unroll
        for (int r = 0; r < 4; r++) ov[r] = (__bf16)o_acc[nt][r];
        *(bf16x4*)&po[(slot << 12) + (size_t)(nt * 16 + ln) * 64 + w * 16 + q * 4] = ov;
    }
}

// ---------------- fused split-KV combine + residual + LayerNorm (bf16 stream) ----------------
__global__ __launch_bounds__(256) void add_ln_attn_kernel(__bf16* __restrict__ hb,
    const __bf16* __restrict__ po, const float* __restrict__ pden,
    const float* __restrict__ g, const float* __restrict__ b)
{
    int w = threadIdx.x >> 6, lane = threadIdx.x & 63;
    int row = (blockIdx.x << 2) + w;          // n*1024 + t
    int n = row >> 10, t = row & (TT - 1);
    int qt = t >> 6, qrow = t & 63;
    int hh = lane >> 3;
    int d0 = (lane & 7) * 8;
    size_t base_nh = (size_t)(n * NHD + hh) * NCHUNK;

    size_t sa = base_nh + C_UA[qt];
    bf16x8 va = *(const bf16x8*)(po + (sa << 12) + (size_t)qrow * 64 + d0);
    float den = pden[sa * 64 + qrow];
    f32x4 a0, a1;
    #pragma unroll
    for (int i = 0; i < 4; i++) { a0[i] = (float)va[i]; a1[i] = (float)va[4 + i]; }
    if (qt >= 8) {
        size_t sb = base_nh + C_UB[qt];
        bf16x8 vb = *(const bf16x8*)(po + (sb << 12) + (size_t)qrow * 64 + d0);
        #pragma unroll
        for (int i = 0; i < 4; i++) { a0[i] += (float)vb[i]; a1[i] += (float)vb[4 + i]; }
        den += pden[sb * 64 + qrow];
    }
    float inv = 1.0f / den;

    size_t base = (size_t)row * DM + lane * 8;
    bf16x8 hv = *(const bf16x8*)(hb + base);
    f32x4 x0, x1;
    #pragma unroll
    for (int i = 0; i < 4; i++) {
        x0[i] = (float)hv[i]     + a0[i] * inv;
        x1[i] = (float)hv[4 + i] + a1[i] * inv;
    }

    float s1 = x0[0]+x0[1]+x0[2]+x0[3] + x1[0]+x1[1]+x1[2]+x1[3];
    float s2 = x0[0]*x0[0]+x0[1]*x0[1]+x0[2]*x0[2]+x0[3]*x0[3]
             + x1[0]*x1[0]+x1[1]*x1[1]+x1[2]*x1[2]+x1[3]*x1[3];
    #pragma unroll
    for (int m = 1; m < 64; m <<= 1) {
        s1 += __shfl_xor(s1, m, 64);
        s2 += __shfl_xor(s2, m, 64);
    }
    float mean = s1 * (1.0f / 512.0f);
    float var = s2 * (1.0f / 512.0f) - mean * mean;
    float rstd = rsqrtf(var + 1e-3f);

    f32x4 gg0 = *(const f32x4*)&g[lane * 8];
    f32x4 gg1 = *(const f32x4*)&g[lane * 8 + 4];
    f32x4 bb0 = *(const f32x4*)&b[lane * 8];
    f32x4 bb1 = *(const f32x4*)&b[lane * 8 + 4];
    bf16x8 pb;
    #pragma unroll
    for (int i = 0; i < 4; i++) {
        pb[i]     = (__bf16)(gg0[i] * ((x0[i] - mean) * rstd) + bb0[i]);
        pb[4 + i] = (__bf16)(gg1[i] * ((x1[i] - mean) * rstd) + bb1[i]);
    }
    *(bf16x8*)(hb + base) = pb;
}

// ---------------- residual add (bf16 ff out) + LayerNorm (bf16 stream) ----------------
// fout != nullptr on the final layer: also writes the f32 output tensor.
__global__ __launch_bounds__(256) void add_ln_kernel(__bf16* __restrict__ hb,
    const __bf16* __restrict__ a, const float* __restrict__ g, const float* __restrict__ b,
    float* __restrict__ fout)
{
    int w = threadIdx.x >> 6, lane = threadIdx.x & 63;
    int row = (blockIdx.x << 2) + w;
    size_t base = (size_t)row * DM + lane * 8;
    bf16x8 hv = *(const bf16x8*)(hb + base);
    bf16x8 av = *(const bf16x8*)(a + base);
    f32x4 x0, x1;
    #pragma unroll
    for (int i = 0; i < 4; i++) {
        x0[i] = (float)hv[i]     + (float)av[i];
        x1[i] = (float)hv[4 + i] + (float)av[4 + i];
    }
    float s1 = x0[0]+x0[1]+x0[2]+x0[3] + x1[0]+x1[1]+x1[2]+x1[3];
    float s2 = x0[0]*x0[0]+x0[1]*x0[1]+x0[2]*x0[2]+x0[3]*x0[3]
             + x1[0]*x1[0]+x1[1]*x1[1]+x1[2]*x1[2]+x1[3]*x1[3];
    #pragma unroll
    for (int m = 1; m < 64; m <<= 1) {
        s1 += __shfl_xor(s1, m, 64);
        s2 += __shfl_xor(s2, m, 64);
    }
    float mean = s1 * (1.0f / 512.0f);
    float var = s2 * (1.0f / 512.0f) - mean * mean;
    float rstd = rsqrtf(var + 1e-3f);
    f32x4 gg0 = *(const f32x4*)&g[lane * 8];
    f32x4 gg1 = *(const f32x4*)&g[lane * 8 + 4];
    f32x4 bb0 = *(const f32x4*)&b[lane * 8];
    f32x4 bb1 = *(const f32x4*)&b[lane * 8 + 4];
    f32x4 o0, o1;
    bf16x8 pb;
    #pragma unroll
    for (int i = 0; i < 4; i++) {
        o0[i] = gg0[i] * ((x0[i] - mean) * rstd) + bb0[i];
        o1[i] = gg1[i] * ((x1[i] - mean) * rstd) + bb1[i];
        pb[i] = (__bf16)o0[i];
        pb[4 + i] = (__bf16)o1[i];
    }
    *(bf16x8*)(hb + base) = pb;
    if (fout) {
        *(f32x4*)&fout[base] = o0;
        *(f32x4*)&fout[base + 4] = o1;
    }
}

extern "C" void kernel_launch(void* const* d_in, const int* in_sizes, int n_in,
                              void* d_out, int out_size, void* d_ws, size_t ws_size,
                              hipStream_t stream) {
    const int*   x     = (const int*)d_in[0];
    const float* emb   = (const float*)d_in[1];
    const float* Wqkv  = (const float*)d_in[2];
    const float* bqkv  = (const float*)d_in[3];
    const float* Wff   = (const float*)d_in[4];
    const float* bff   = (const float*)d_in[5];
    const float* Wo    = (const float*)d_in[6];
    const float* bo    = (const float*)d_in[7];
    const float* g1    = (const float*)d_in[8];
    const float* beta1 = (const float*)d_in[9];
    const float* g2    = (const float*)d_in[10];
    const float* beta2 = (const float*)d_in[11];

    char* w = (char*)d_ws;
    __bf16* qkvb = (__bf16*)w;                        // 12,582,912 B (Q|K|V^T bf16)
    __bf16* ffb  = (__bf16*)w;                        // aliases qkv (dead after attn)
    __bf16* abuf = (__bf16*)(w + 25165824);           //  4,194,304 B (FF2 out, bf16)
    __bf16* hb   = (__bf16*)(w + 33554432);           //  4,194,304 B (bf16 residual stream)
    __bf16* WtQ  = (__bf16*)(w + 37748736);           //  9,437,184 B  [L][1536][512] (perm'd rows)
    __bf16* WtF  = (__bf16*)(w + 47185920);           //  6,291,456 B  [L][1024][512]
    __bf16* WtO  = (__bf16*)(w + 53477376);           //  6,291,456 B  [L][512][1024]
    __bf16* po   = (__bf16*)(w + 59768832);           //  6,291,456 B  [32*24][64][64] bf16
    float*  pden = (float*)(w + 80740352);            //    196,608 B  [32*24][64]
    float*  bqkv_p = (float*)(w + 81068032);          //     36,864 B  [L][1536] perm'd bias

    convert_all_kernel<<<dim3(1792, 1, LAYERS), 256, 0, stream>>>(
        Wqkv, Wff, Wo, bqkv, WtQ, WtF, WtO, bqkv_p);

    embed_pos_kernel<<<MROWS, 256, 0, stream>>>(x, emb, hb);

    for (int l = 0; l < LAYERS; l++) {
        const float* bff_l  = bff  + (size_t)l * DFFD;
        const float* bo_l   = bo   + (size_t)l * DM;

        // QKV projection: 64x64 tiles -> 1536 blocks (6/CU)
        gemm2p<64, 64, 2><<<dim3(24, 64), 256, 0, stream>>>(
            hb, WtQ + (size_t)l * 1536 * 512, bqkv_p + l * 1536, qkvb, MROWS, 3 * DM, 512);

        attn_partial_kernel<<<dim3(NCHUNK, NB * NHD), 256, 0, stream>>>(
            qkvb, qkvb + PERBUF, qkvb + 2 * (size_t)PERBUF, po, pden);

        // fused: combine split-KV partials + residual + LN1 (bf16 stream)
        add_ln_attn_kernel<<<MROWS / 4, 256, 0, stream>>>(
            hb, po, pden, g1 + l * DM, beta1 + l * DM);

        // FF1: relu(h @ Wff + bff) -> bf16; 64x64 tiles -> 1024 blocks (4/CU)
        gemm2p<64, 64, 1><<<dim3(16, 64), 256, 0, stream>>>(
            hb, WtF + (size_t)l * 1024 * 512, bff_l, ffb, MROWS, DFFD, 512);

        // FF2: ff @ Wo + bo -> bf16; 64x64 tiles -> 512 blocks (2/CU)
        gemm2p<64, 64, 0><<<dim3(8, 64), 256, 0, stream>>>(
            ffb, WtO + (size_t)l * 512 * 1024, bo_l, abuf, MROWS, DM, 1024);

        // residual + LN2; final layer also writes the f32 output
        add_ln_kernel<<<MROWS / 4, 256, 0, stream>>>(
            hb, abuf, g2 + l * DM, beta2 + l * DM,
            (l == LAYERS - 1) ? (float*)d_out : nullptr);
    }
}

// Round 12
// 592.008 us; speedup vs baseline: 1.0189x; 1.0189x over previous
//
#include <hip/hip_runtime.h>
#include <hip/hip_bf16.h>
#include <math.h>

#define DM   512
#define TT   1024
#define NB   4
#define NHD  8
#define LAYERS 6
#define DFFD 1024
#define MROWS (NB*TT)          // 4096
#define PERBUF (NB*NHD*TT*64)  // 2097152 elems per Q/K/V buffer

typedef __bf16 bf16x8 __attribute__((ext_vector_type(8)));
typedef __bf16 bf16x4 __attribute__((ext_vector_type(4)));
typedef float f32x4 __attribute__((ext_vector_type(4)));

// async global->LDS, 16B per lane; LDS base must be wave-uniform (m104/m108)
__device__ __forceinline__ void gl_lds16(const __bf16* g, __bf16* l) {
    __builtin_amdgcn_global_load_lds((const __attribute__((address_space(1))) void*)g,
                                     (__attribute__((address_space(3))) void*)l, 16, 0, 0);
}

// split-KV chunk tables (NCHUNK=24): qt 0-7 one chunk, qt 8-15 two chunks.
// Ordered heavy-first (u=0 dispatched first carries longest chains).
__constant__ signed char C_QT[24]  = {15,15,14, 7,14,13,13,12, 6,12,11,11,10, 5,10, 9, 9, 8, 4, 8, 3, 2, 1, 0};
__constant__ signed char C_ST0[24] = { 0, 8, 0, 0, 8, 0, 7, 0, 0, 7, 0, 6, 0, 0, 6, 0, 5, 0, 0, 5, 0, 0, 0, 0};
__constant__ signed char C_ST1[24] = { 8,16, 8, 8,15, 7,14, 7, 7,13, 6,12, 6, 6,11, 5,10, 5, 5, 9, 4, 3, 2, 1};
// combine: qt -> chunk ids (second valid only for qt>=8)
__constant__ unsigned char C_UA[16] = {23,22,21,20,18,13,8,3,17,15,12,10,7,5,2,0};
__constant__ unsigned char C_UB[16] = { 0, 0, 0, 0, 0, 0,0,0,19,16,14,11,9,6,4,1};
#define NCHUNK 24

// ---------------- embedding + positional encoding (bf16 residual stream) ----------------
__global__ __launch_bounds__(256) void embed_pos_kernel(const int* __restrict__ x,
    const float* __restrict__ emb, __bf16* __restrict__ hb)
{
    int row = blockIdx.x;            // n*T + t
    int t = row & (TT - 1);
    int tok = x[row];
    const float* e = emb + (size_t)tok * DM;
    __bf16* outb = hb + (size_t)row * DM;
    for (int i = threadIdx.x; i < DM; i += 256) {
        float val = e[i] * 22.62741699796952f;   // sqrt(512)
        int pair = i >> 1;
        // 10000^(-pair/256) = exp2(-pair * log2(10000)/256)
        float rate = exp2f((float)pair * -0.051905126482615035f);
        float ang = (float)t * rate;
        float pe = (i & 1) ? __cosf(ang) : __sinf(ang);
        outb[i] = (__bf16)(val + pe);
    }
}

// ---------------- all-weight convert + transpose (one dispatch) ----------------
// W[K,N] fp32 -> Wt[N,K] bf16. For Wqkv, output columns are PERMUTED:
// original col c -> row (c%3)*512 + c/3, grouping Q|K|V with inner [h][d].
__global__ __launch_bounds__(256) void convert_all_kernel(
    const float* __restrict__ Wqkv, const float* __restrict__ Wff, const float* __restrict__ Wo,
    const float* __restrict__ bqkv,
    __bf16* __restrict__ WtQ, __bf16* __restrict__ WtF, __bf16* __restrict__ WtO,
    float* __restrict__ bqkv_p)
{
    __shared__ float tile[32][33];
    int l = blockIdx.z;
    int t = blockIdx.x;
    const float* W; __bf16* Wt; int K, N, bx, by; bool perm = false;
    if (t < 768)       { W = Wqkv; Wt = WtQ; K = 512;  N = 1536; bx = t & 15;  by = t >> 4; perm = true; }
    else if (t < 1280) { int u = t - 768;  W = Wff; Wt = WtF; K = 512;  N = 1024; bx = u & 15; by = u >> 4; }
    else               { int u = t - 1280; W = Wo;  Wt = WtO; K = 1024; N = 512;  bx = u & 31; by = u >> 5; }
    int k0 = bx * 32, n0 = by * 32;
    const float* Wl = W + (size_t)l * K * N;
    __bf16* Wtl = Wt + (size_t)l * K * N;
    int tx = threadIdx.x & 31, ty = threadIdx.x >> 5;   // ty 0..7
    #pragma unroll
    for (int i = ty; i < 32; i += 8)
        tile[i][tx] = Wl[(size_t)(k0 + i) * N + n0 + tx];
    if (perm && bx == 0 && ty == 0) {                   // permute bias once per col-chunk
        int c = n0 + tx;
        bqkv_p[l * 1536 + (c % 3) * 512 + c / 3] = bqkv[(size_t)l * 1536 + c];
    }
    __syncthreads();
    #pragma unroll
    for (int i = ty; i < 32; i += 8) {
        int c = n0 + i;
        int row = perm ? ((c % 3) * 512 + c / 3) : c;
        Wtl[(size_t)row * K + k0 + tx] = (__bf16)tile[tx][i];
    }
}

// ---------------- bf16 MFMA GEMM, templated tile, 2-phase pipelined 32-K panels ----------------
// R12: reverted to R10-best tile config (128x64 QKV/FF1, 64x64 FF2) — R11 showed
// the occupancy curve peaks at ~3 blocks/CU; 64x64 everywhere regressed (worse
// MFMA:ds ratio + doubled B re-reads). LDS reads swizzled conflict-free (R7).
// Fragment loads via LDS (R4 lesson).
// MODE 0: bf16 C out (+bias, no relu). MODE 1: relu -> bf16. MODE 2: QKV scatter, PERMUTED cols:
// c in [0,512)=Q, [512,1024)=K (both [n,h,t,d]), [1024,1536)=V^T [n,h,d,t].
template<int BM, int BN, int MODE>
__global__ __launch_bounds__(256) void gemm2p(const __bf16* __restrict__ A,
    const __bf16* __restrict__ Bt, const float* __restrict__ bias,
    void* __restrict__ Cv, int M, int Nc, int K)
{
    constexpr int WM = BM / 2, WN = BN / 2;
    constexpr int MT = WM / 16, NT = WN / 16;
    constexpr int ACH = BM / 64;   // 16-row A chunks staged per wave
    constexpr int BCH = BN / 64;   // 16-row B chunks staged per wave
    __shared__ __align__(16) __bf16 As[2][BM * 32];
    __shared__ __align__(16) __bf16 Bs[2][BN * 32];
    int tid = threadIdx.x;
    int lane = tid & 63;
    int wave = tid >> 6;
    int ln = lane & 15, q = lane >> 4;
    int wrow = (wave >> 1) * WM, wcol = (wave & 1) * WN;
    int n0 = blockIdx.x * BN, m0 = blockIdx.y * BM;

    f32x4 acc[MT][NT] = {};

    const __bf16* Ab = A + (size_t)m0 * K;
    const __bf16* Bb = Bt + (size_t)n0 * K;
    int srow = lane >> 2;                                  // 0..15
    int scol = ((lane & 3) ^ ((lane >> 3) & 3)) * 8;       // pre-swizzled source slot
    int kx   = (q ^ ((ln >> 1) & 3)) * 8;                  // read-side swizzled slot

    const __bf16* Aga[ACH];
    const __bf16* Bga[BCH];
    #pragma unroll
    for (int i = 0; i < ACH; i++)
        Aga[i] = Ab + (size_t)(wave * (16 * ACH) + 16 * i + srow) * K + scol;
    #pragma unroll
    for (int i = 0; i < BCH; i++)
        Bga[i] = Bb + (size_t)(wave * (16 * BCH) + 16 * i + srow) * K + scol;

    auto STAGE = [&](int kp, int buf) {
        #pragma unroll
        for (int i = 0; i < ACH; i++)
            gl_lds16(Aga[i] + kp, As[buf] + (wave * (16 * ACH) + 16 * i) * 32);
        #pragma unroll
        for (int i = 0; i < BCH; i++)
            gl_lds16(Bga[i] + kp, Bs[buf] + (wave * (16 * BCH) + 16 * i) * 32);
    };
    auto COMPUTE = [&](int buf) {
        bf16x8 af[MT], bfr[NT];
        #pragma unroll
        for (int mt = 0; mt < MT; mt++)
            af[mt] = *(const bf16x8*)&As[buf][(wrow + mt * 16 + ln) * 32 + kx];
        #pragma unroll
        for (int nt = 0; nt < NT; nt++)
            bfr[nt] = *(const bf16x8*)&Bs[buf][(wcol + nt * 16 + ln) * 32 + kx];
        #pragma unroll
        for (int mt = 0; mt < MT; mt++)
            #pragma unroll
            for (int nt = 0; nt < NT; nt++)
                acc[mt][nt] = __builtin_amdgcn_mfma_f32_16x16x32_bf16(af[mt], bfr[nt], acc[mt][nt], 0, 0, 0);
    };

    STAGE(0, 0);
    __syncthreads();
    int kp = 0;
    for (; kp + 64 < K; kp += 64) {
        STAGE(kp + 32, 1);
        COMPUTE(0);
        __syncthreads();      // drain: panel kp+32 landed; buf0 readers done
        STAGE(kp + 64, 0);
        COMPUTE(1);
        __syncthreads();      // drain: panel kp+64 landed; buf1 readers done
    }
    STAGE(kp + 32, 1);
    COMPUTE(0);
    __syncthreads();
    COMPUTE(1);

    #pragma unroll
    for (int mt = 0; mt < MT; mt++) {
        int mbase = m0 + wrow + mt * 16 + q * 4;
        if constexpr (MODE == 0) {
            __bf16* Cb = (__bf16*)Cv;
            #pragma unroll
            for (int r = 0; r < 4; r++) {
                int m = mbase + r;
                #pragma unroll
                for (int nt = 0; nt < NT; nt++) {
                    int c = n0 + wcol + nt * 16 + ln;
                    Cb[(size_t)m * Nc + c] = (__bf16)(acc[mt][nt][r] + bias[c]);
                }
            }
        } else if constexpr (MODE == 1) {
            __bf16* Cb = (__bf16*)Cv;
            #pragma unroll
            for (int r = 0; r < 4; r++) {
                int m = mbase + r;
                #pragma unroll
                for (int nt = 0; nt < NT; nt++) {
                    int c = n0 + wcol + nt * 16 + ln;
                    float val = acc[mt][nt][r] + bias[c];
                    Cb[(size_t)m * Nc + c] = (__bf16)fmaxf(val, 0.f);
                }
            }
        } else {
            __bf16* Cb = (__bf16*)Cv;
            int n = mbase >> 10, t = mbase & (TT - 1);
            #pragma unroll
            for (int nt = 0; nt < NT; nt++) {
                int c = n0 + wcol + nt * 16 + ln;
                int buf = c >> 9;            // uniform within the 16-col group
                int hd = c & 511;
                int hh = hd >> 6, d = hd & 63;
                float bv = bias[c];
                if (buf == 2) {              // V^T [n,h,d,t]: 4 consecutive t -> one 8B store
                    size_t idx = 2 * (size_t)PERBUF + (((size_t)(n * NHD + hh) * 64 + d) << 10) + t;
                    bf16x4 v4;
                    #pragma unroll
                    for (int r = 0; r < 4; r++) v4[r] = (__bf16)(acc[mt][nt][r] + bv);
                    *(bf16x4*)&Cb[idx] = v4;
                } else {                     // Q,K [n,h,t,d]
                    size_t base = (size_t)buf * PERBUF + (((size_t)(n * NHD + hh) * TT + t) << 6) + d;
                    #pragma unroll
                    for (int r = 0; r < 4; r++)
                        Cb[base + (size_t)(r << 6)] = (__bf16)(acc[mt][nt][r] + bv);
                }
            }
        }
    }
}

// ---------------- split-KV MFMA flash attention (NCHUNK=24, table-driven) ----------------
// Q fragments in registers. K single-buffered + V double-buffered in LDS via
// async global_load_lds with XOR-swizzled source (linear dest, swizzled read).
// QK^T computed SWAPPED (S^T = K Q^T): lane holds 4 consecutive s per q-row ->
// P store is 4x bf16x4, den reduction 2 shuffles. 768 blocks (3/CU), chains <= 8.
// po partials stored BF16 (R8): MFMA accum stays f32.
#define PPAD 72
__global__ __launch_bounds__(256) void attn_partial_kernel(const __bf16* __restrict__ qb,
    const __bf16* __restrict__ kb, const __bf16* __restrict__ vtb,
    __bf16* __restrict__ po, float* __restrict__ pden)
{
    __shared__ __align__(16) __bf16 Ksh[64 * 64];      // K tile [s][d], swizzled
    __shared__ __align__(16) __bf16 Vsh[2][64 * 64];   // V^T tile [d][s], swizzled
    __shared__ __align__(16) __bf16 Ps[64 * PPAD];     // P tile [q][s], padded

    int u = blockIdx.x;                  // heavy chunks at low u (dispatch first)
    int nh = blockIdx.y;
    int qt  = C_QT[u];
    int st0 = C_ST0[u];
    int st1 = C_ST1[u];

    int tid = threadIdx.x;
    int lane = tid & 63, w = tid >> 6;
    int ln = lane & 15, q = lane >> 4;

    const __bf16* Kg = kb + (size_t)nh * TT * 64;
    const __bf16* Vg = vtb + (size_t)nh * 64 * TT;   // [d][t]

    // Q fragments in registers: wave w owns q-rows w*16..+16 of this q-tile
    const __bf16* Qrow = qb + ((size_t)nh * TT + (size_t)qt * 64 + w * 16 + ln) * 64;
    bf16x8 aq0 = *(const bf16x8*)(Qrow + q * 8);
    bf16x8 aq1 = *(const bf16x8*)(Qrow + 32 + q * 8);

    // staging geometry: wave w issue i covers LDS bytes [(w*2+i)*1024, +1024)
    // lane l -> row (w*2+i)*8 + (l>>3), col16 l&7; source col pre-swizzled.
    int srow = lane >> 3;                        // 0..7  == (row & 7)
    int swz  = ((lane & 7) ^ srow) << 3;         // swizzled source col (elems)
    int r0 = (w * 2 + 0) * 8 + srow;
    int r1 = (w * 2 + 1) * 8 + srow;
    const __bf16* Kg0 = Kg + (size_t)r0 * 64 + swz;
    const __bf16* Kg1 = Kg + (size_t)r1 * 64 + swz;
    const __bf16* Vg0 = Vg + (size_t)r0 * TT + swz;
    const __bf16* Vg1 = Vg + (size_t)r1 * TT + swz;
    __bf16* Kd0 = Ksh + (w * 2 + 0) * 512;
    __bf16* Kd1 = Ksh + (w * 2 + 1) * 512;

    f32x4 o_acc[4] = {};
    float den_lane = 0.f;          // partial softmax denom for q-row w*16+ln
    int qrow_l = w * 16 + ln;

    int cur = 0;
    gl_lds16(Kg0 + st0 * 4096, Kd0);
    gl_lds16(Kg1 + st0 * 4096, Kd1);
    gl_lds16(Vg0 + st0 * 64, Vsh[0] + (w * 2 + 0) * 512);
    gl_lds16(Vg1 + st0 * 64, Vsh[0] + (w * 2 + 1) * 512);

    int kswz = ln & 7;   // row&7 for all swizzled reads below (rows stride 16)
    for (int st = st0; st < st1; st++) {
        __syncthreads();   // staged K/V landed (vmcnt drain); prior P/V readers done

        // S^T = K Q^T: wave w computes S^T[all 64 s][its 16 q-cols]
        f32x4 st_acc[4] = {};
        #pragma unroll
        for (int mt = 0; mt < 4; mt++) {
            int r = mt * 16 + ln;
            bf16x8 k0v = *(const bf16x8*)&Ksh[r * 64 + ((q ^ kswz) << 3)];
            st_acc[mt] = __builtin_amdgcn_mfma_f32_16x16x32_bf16(k0v, aq0, st_acc[mt], 0, 0, 0);
            bf16x8 k1v = *(const bf16x8*)&Ksh[r * 64 + (((q + 4) ^ kswz) << 3)];
            st_acc[mt] = __builtin_amdgcn_mfma_f32_16x16x32_bf16(k1v, aq1, st_acc[mt], 0, 0, 0);
        }

        // P = exp(S/8), causal mask on diagonal tile. Lane holds 4 consecutive s
        // (mt*16 + q*4 + r) for its q-row -> one bf16x4 store per mt.
        bool diag = (st == qt);
        #pragma unroll
        for (int mt = 0; mt < 4; mt++) {
            int s0i = mt * 16 + q * 4;
            bf16x4 p4;
            #pragma unroll
            for (int r = 0; r < 4; r++) {
                float p;
                if (diag && (s0i + r) > qrow_l) p = 0.f;
                else p = exp2f(st_acc[mt][r] * 0.18033688011112042f);  // /8 * log2(e)
                den_lane += p;
                p4[r] = (__bf16)p;
            }
            *(bf16x4*)&Ps[qrow_l * PPAD + s0i] = p4;
        }
        __syncthreads();   // P visible; all waves done reading K

        if (st + 1 < st1) {   // prefetch next tile under PV (K dead, V alt buffer)
            gl_lds16(Kg0 + (st + 1) * 4096, Kd0);
            gl_lds16(Kg1 + (st + 1) * 4096, Kd1);
            gl_lds16(Vg0 + (st + 1) * 64, Vsh[cur ^ 1] + (w * 2 + 0) * 512);
            gl_lds16(Vg1 + (st + 1) * 64, Vsh[cur ^ 1] + (w * 2 + 1) * 512);
        }

        // O^T += V^T P^T : wave w owns d-rows w*16..+16, all 64 q-cols
        #pragma unroll
        for (int ks = 0; ks < 2; ks++) {
            bf16x8 af = *(const bf16x8*)&Vsh[cur][(w * 16 + ln) * 64 + (((ks * 4 + q) ^ kswz) << 3)];
            #pragma unroll
            for (int nt = 0; nt < 4; nt++) {
                bf16x8 bfr = *(const bf16x8*)&Ps[(nt * 16 + ln) * PPAD + ks * 32 + q * 8];
                o_acc[nt] = __builtin_amdgcn_mfma_f32_16x16x32_bf16(af, bfr, o_acc[nt], 0, 0, 0);
            }
        }
        cur ^= 1;
    }

    // den: lanes {ln, ln+16, ln+32, ln+48} hold s-partitions of q-row w*16+ln
    den_lane += __shfl_xor(den_lane, 16, 64);
    den_lane += __shfl_xor(den_lane, 32, 64);
    size_t slot = (size_t)nh * NCHUNK + u;
    if (lane < 16)
        pden[slot * 64 + qrow_l] = den_lane;

    #pragma unroll
    for (int nt = 0; nt < 4; nt++) {
        bf16x4 ov;
        #pragma unroll
        for (int r = 0; r < 4; r++) ov[r] = (__bf16)o_acc[nt][r];
        *(bf16x4*)&po[(slot << 12) + (size_t)(nt * 16 + ln) * 64 + w * 16 + q * 4] = ov;
    }
}

// ---------------- fused split-KV combine + residual + LayerNorm (bf16 stream) ----------------
__global__ __launch_bounds__(256) void add_ln_attn_kernel(__bf16* __restrict__ hb,
    const __bf16* __restrict__ po, const float* __restrict__ pden,
    const float* __restrict__ g, const float* __restrict__ b)
{
    int w = threadIdx.x >> 6, lane = threadIdx.x & 63;
    int row = (blockIdx.x << 2) + w;          // n*1024 + t
    int n = row >> 10, t = row & (TT - 1);
    int qt = t >> 6, qrow = t & 63;
    int hh = lane >> 3;
    int d0 = (lane & 7) * 8;
    size_t base_nh = (size_t)(n * NHD + hh) * NCHUNK;

    size_t sa = base_nh + C_UA[qt];
    bf16x8 va = *(const bf16x8*)(po + (sa << 12) + (size_t)qrow * 64 + d0);
    float den = pden[sa * 64 + qrow];
    f32x4 a0, a1;
    #pragma unroll
    for (int i = 0; i < 4; i++) { a0[i] = (float)va[i]; a1[i] = (float)va[4 + i]; }
    if (qt >= 8) {
        size_t sb = base_nh + C_UB[qt];
        bf16x8 vb = *(const bf16x8*)(po + (sb << 12) + (size_t)qrow * 64 + d0);
        #pragma unroll
        for (int i = 0; i < 4; i++) { a0[i] += (float)vb[i]; a1[i] += (float)vb[4 + i]; }
        den += pden[sb * 64 + qrow];
    }
    float inv = 1.0f / den;

    size_t base = (size_t)row * DM + lane * 8;
    bf16x8 hv = *(const bf16x8*)(hb + base);
    f32x4 x0, x1;
    #pragma unroll
    for (int i = 0; i < 4; i++) {
        x0[i] = (float)hv[i]     + a0[i] * inv;
        x1[i] = (float)hv[4 + i] + a1[i] * inv;
    }

    float s1 = x0[0]+x0[1]+x0[2]+x0[3] + x1[0]+x1[1]+x1[2]+x1[3];
    float s2 = x0[0]*x0[0]+x0[1]*x0[1]+x0[2]*x0[2]+x0[3]*x0[3]
             + x1[0]*x1[0]+x1[1]*x1[1]+x1[2]*x1[2]+x1[3]*x1[3];
    #pragma unroll
    for (int m = 1; m < 64; m <<= 1) {
        s1 += __shfl_xor(s1, m, 64);
        s2 += __shfl_xor(s2, m, 64);
    }
    float mean = s1 * (1.0f / 512.0f);
    float var = s2 * (1.0f / 512.0f) - mean * mean;
    float rstd = rsqrtf(var + 1e-3f);

    f32x4 gg0 = *(const f32x4*)&g[lane * 8];
    f32x4 gg1 = *(const f32x4*)&g[lane * 8 + 4];
    f32x4 bb0 = *(const f32x4*)&b[lane * 8];
    f32x4 bb1 = *(const f32x4*)&b[lane * 8 + 4];
    bf16x8 pb;
    #pragma unroll
    for (int i = 0; i < 4; i++) {
        pb[i]     = (__bf16)(gg0[i] * ((x0[i] - mean) * rstd) + bb0[i]);
        pb[4 + i] = (__bf16)(gg1[i] * ((x1[i] - mean) * rstd) + bb1[i]);
    }
    *(bf16x8*)(hb + base) = pb;
}

// ---------------- residual add (bf16 ff out) + LayerNorm (bf16 stream) ----------------
// fout != nullptr on the final layer: also writes the f32 output tensor.
__global__ __launch_bounds__(256) void add_ln_kernel(__bf16* __restrict__ hb,
    const __bf16* __restrict__ a, const float* __restrict__ g, const float* __restrict__ b,
    float* __restrict__ fout)
{
    int w = threadIdx.x >> 6, lane = threadIdx.x & 63;
    int row = (blockIdx.x << 2) + w;
    size_t base = (size_t)row * DM + lane * 8;
    bf16x8 hv = *(const bf16x8*)(hb + base);
    bf16x8 av = *(const bf16x8*)(a + base);
    f32x4 x0, x1;
    #pragma unroll
    for (int i = 0; i < 4; i++) {
        x0[i] = (float)hv[i]     + (float)av[i];
        x1[i] = (float)hv[4 + i] + (float)av[4 + i];
    }
    float s1 = x0[0]+x0[1]+x0[2]+x0[3] + x1[0]+x1[1]+x1[2]+x1[3];
    float s2 = x0[0]*x0[0]+x0[1]*x0[1]+x0[2]*x0[2]+x0[3]*x0[3]
             + x1[0]*x1[0]+x1[1]*x1[1]+x1[2]*x1[2]+x1[3]*x1[3];
    #pragma unroll
    for (int m = 1; m < 64; m <<= 1) {
        s1 += __shfl_xor(s1, m, 64);
        s2 += __shfl_xor(s2, m, 64);
    }
    float mean = s1 * (1.0f / 512.0f);
    float var = s2 * (1.0f / 512.0f) - mean * mean;
    float rstd = rsqrtf(var + 1e-3f);
    f32x4 gg0 = *(const f32x4*)&g[lane * 8];
    f32x4 gg1 = *(const f32x4*)&g[lane * 8 + 4];
    f32x4 bb0 = *(const f32x4*)&b[lane * 8];
    f32x4 bb1 = *(const f32x4*)&b[lane * 8 + 4];
    f32x4 o0, o1;
    bf16x8 pb;
    #pragma unroll
    for (int i = 0; i < 4; i++) {
        o0[i] = gg0[i] * ((x0[i] - mean) * rstd) + bb0[i];
        o1[i] = gg1[i] * ((x1[i] - mean) * rstd) + bb1[i];
        pb[i] = (__bf16)o0[i];
        pb[4 + i] = (__bf16)o1[i];
    }
    *(bf16x8*)(hb + base) = pb;
    if (fout) {
        *(f32x4*)&fout[base] = o0;
        *(f32x4*)&fout[base + 4] = o1;
    }
}

extern "C" void kernel_launch(void* const* d_in, const int* in_sizes, int n_in,
                              void* d_out, int out_size, void* d_ws, size_t ws_size,
                              hipStream_t stream) {
    const int*   x     = (const int*)d_in[0];
    const float* emb   = (const float*)d_in[1];
    const float* Wqkv  = (const float*)d_in[2];
    const float* bqkv  = (const float*)d_in[3];
    const float* Wff   = (const float*)d_in[4];
    const float* bff   = (const float*)d_in[5];
    const float* Wo    = (const float*)d_in[6];
    const float* bo    = (const float*)d_in[7];
    const float* g1    = (const float*)d_in[8];
    const float* beta1 = (const float*)d_in[9];
    const float* g2    = (const float*)d_in[10];
    const float* beta2 = (const float*)d_in[11];

    char* w = (char*)d_ws;
    __bf16* qkvb = (__bf16*)w;                        // 12,582,912 B (Q|K|V^T bf16)
    __bf16* ffb  = (__bf16*)w;                        // aliases qkv (dead after attn)
    __bf16* abuf = (__bf16*)(w + 25165824);           //  4,194,304 B (FF2 out, bf16)
    __bf16* hb   = (__bf16*)(w + 33554432);           //  4,194,304 B (bf16 residual stream)
    __bf16* WtQ  = (__bf16*)(w + 37748736);           //  9,437,184 B  [L][1536][512] (perm'd rows)
    __bf16* WtF  = (__bf16*)(w + 47185920);           //  6,291,456 B  [L][1024][512]
    __bf16* WtO  = (__bf16*)(w + 53477376);           //  6,291,456 B  [L][512][1024]
    __bf16* po   = (__bf16*)(w + 59768832);           //  6,291,456 B  [32*24][64][64] bf16
    float*  pden = (float*)(w + 80740352);            //    196,608 B  [32*24][64]
    float*  bqkv_p = (float*)(w + 81068032);          //     36,864 B  [L][1536] perm'd bias

    convert_all_kernel<<<dim3(1792, 1, LAYERS), 256, 0, stream>>>(
        Wqkv, Wff, Wo, bqkv, WtQ, WtF, WtO, bqkv_p);

    embed_pos_kernel<<<MROWS, 256, 0, stream>>>(x, emb, hb);

    for (int l = 0; l < LAYERS; l++) {
        const float* bff_l  = bff  + (size_t)l * DFFD;
        const float* bo_l   = bo   + (size_t)l * DM;

        // QKV projection: 128x64 tiles -> 768 blocks (3/CU)
        gemm2p<128, 64, 2><<<dim3(24, 32), 256, 0, stream>>>(
            hb, WtQ + (size_t)l * 1536 * 512, bqkv_p + l * 1536, qkvb, MROWS, 3 * DM, 512);

        attn_partial_kernel<<<dim3(NCHUNK, NB * NHD), 256, 0, stream>>>(
            qkvb, qkvb + PERBUF, qkvb + 2 * (size_t)PERBUF, po, pden);

        // fused: combine split-KV partials + residual + LN1 (bf16 stream)
        add_ln_attn_kernel<<<MROWS / 4, 256, 0, stream>>>(
            hb, po, pden, g1 + l * DM, beta1 + l * DM);

        // FF1: relu(h @ Wff + bff) -> bf16; 128x64 tiles -> 512 blocks (2/CU)
        gemm2p<128, 64, 1><<<dim3(16, 32), 256, 0, stream>>>(
            hb, WtF + (size_t)l * 1024 * 512, bff_l, ffb, MROWS, DFFD, 512);

        // FF2: ff @ Wo + bo -> bf16; 64x64 tiles -> 512 blocks (2/CU)
        gemm2p<64, 64, 0><<<dim3(8, 64), 256, 0, stream>>>(
            ffb, WtO + (size_t)l * 512 * 1024, bo_l, abuf, MROWS, DM, 1024);

        // residual + LN2; final layer also writes the f32 output
        add_ln_kernel<<<MROWS / 4, 256, 0, stream>>>(
            hb, abuf, g2 + l * DM, beta2 + l * DM,
            (l == LAYERS - 1) ? (float*)d_out : nullptr);
    }
}